// Round 1
// baseline (239.970 us; speedup 1.0000x reference)
//
#include <hip/hip_runtime.h>
#include <cstdint>

#define NT 512
#define MT 8

// ws float offsets
static constexpr int C0_OFF = 0;          // conn0: 8*32*325 = 83200
static constexpr int C1_OFF = 83200;      // conn1: 50*26*52 = 67600
static constexpr int C2_OFF = 150800;     // conn2: 67600
static constexpr int CF_OFF = 218400;     // gate coeffs: 3*1300*4 = 15600
static constexpr int WS_FLOATS = 234000;  // ~936 KB

// ---------------------------------------------------------------------------
// Precompute: softmax the interconnect weights (axis=1) and collapse the
// 16-gate softmax-weighted bank to 4 affine coefficients per column:
//   gate16(A,B) = alpha + beta*A + gamma*B + delta*(A*B)
// ---------------------------------------------------------------------------
__global__ void precompute_kernel(const float* __restrict__ c0,
                                  const float* __restrict__ w0,
                                  const float* __restrict__ c1,
                                  const float* __restrict__ w1,
                                  const float* __restrict__ c2,
                                  const float* __restrict__ w2,
                                  float* __restrict__ ws) {
  int id = blockIdx.x * blockDim.x + threadIdx.x;
  if (id < 2600) {  // conn0 columns (n,o): softmax over m=32, stride 325
    int n = id / 325, o = id - n * 325;
    const float* src = c0 + n * (32 * 325) + o;
    float v[32]; float mx = -3.4e38f;
#pragma unroll
    for (int m = 0; m < 32; ++m) { v[m] = src[m * 325]; mx = fmaxf(mx, v[m]); }
    float ssum = 0.f;
#pragma unroll
    for (int m = 0; m < 32; ++m) { v[m] = __expf(v[m] - mx); ssum += v[m]; }
    float inv = 1.f / ssum;
    float* dst = ws + C0_OFF + n * (32 * 325) + o;
#pragma unroll
    for (int m = 0; m < 32; ++m) dst[m * 325] = v[m] * inv;
    return;
  }
  id -= 2600;
  if (id < 5200) {  // conn1 / conn2 columns: softmax over m=26, stride 52
    const float* src0 = (id < 2600) ? c1 : c2;
    float* dst0 = ws + ((id < 2600) ? C1_OFF : C2_OFF);
    int col = (id < 2600) ? id : id - 2600;
    int n = col / 52, o = col - n * 52;
    const float* src = src0 + n * (26 * 52) + o;
    float v[26]; float mx = -3.4e38f;
#pragma unroll
    for (int m = 0; m < 26; ++m) { v[m] = src[m * 52]; mx = fmaxf(mx, v[m]); }
    float ssum = 0.f;
#pragma unroll
    for (int m = 0; m < 26; ++m) { v[m] = __expf(v[m] - mx); ssum += v[m]; }
    float inv = 1.f / ssum;
    float* dst = dst0 + n * (26 * 52) + o;
#pragma unroll
    for (int m = 0; m < 26; ++m) dst[m * 52] = v[m] * inv;
    return;
  }
  id -= 5200;
  if (id < 3900) {  // gate coefficients: layer = id/1300, g = id%1300
    int layer = id / 1300, g = id - layer * 1300;
    const float* w = (layer == 0) ? w0 : ((layer == 1) ? w1 : w2);
    float v[16]; float mx = -3.4e38f;
#pragma unroll
    for (int k = 0; k < 16; ++k) { v[k] = w[k * 1300 + g]; mx = fmaxf(mx, v[k]); }
    float ssum = 0.f;
#pragma unroll
    for (int k = 0; k < 16; ++k) { v[k] = __expf(v[k] - mx); ssum += v[k]; }
    float inv = 1.f / ssum;
#pragma unroll
    for (int k = 0; k < 16; ++k) v[k] *= inv;
    // gates: 0, AB, A-AB, A, B-AB, B, S-AB, S, 1-S, 1-S+AB, 1-B, 1-B+AB,
    //        1-A, 1-A+AB, 1-AB, 1   (S = A+B-AB)
    float alpha = v[8] + v[9] + v[10] + v[11] + v[12] + v[13] + v[14] + v[15];
    float beta  = v[2] + v[3] + v[6] + v[7] - v[8] - v[9] - v[12] - v[13];
    float gamma = v[4] + v[5] + v[6] + v[7] - v[8] - v[9] - v[10] - v[11];
    float delta = v[1] - v[2] - v[4] - 2.f * v[6] - v[7] + v[8] + 2.f * v[9]
                + v[11] + v[13] - v[14];
    reinterpret_cast<float4*>(ws + CF_OFF)[id] =
        make_float4(alpha, beta, gamma, delta);
  }
}

// ---------------------------------------------------------------------------
// Fully fused network: MT=8 samples per workgroup, intermediates in LDS.
//   bufB(x 256) -L1-> bufA(2600) -G-> bufB(1300) -L3-> bufA -G-> bufB
//   -L5-> bufA -G-> bufB -reduce/softmax-> out
// Weights register-reused across all 8 samples (one load feeds 8 FMAs).
// ---------------------------------------------------------------------------
__global__ __launch_bounds__(NT) void fused_kernel(const float* __restrict__ x,
                                                   const float* __restrict__ ws,
                                                   float* __restrict__ out,
                                                   int B) {
  extern __shared__ float smem[];
  float* bufA = smem;                       // [MT][2600]
  float* bufB = smem + MT * 2600;           // [MT][1300]
  float* lg   = smem + MT * 2600 + MT * 1300;  // [MT][10]
  const int tid = threadIdx.x;
  const int s0 = blockIdx.x * MT;

  // ---- load x tile: MT x 256 -> bufB[s][0..255] (one float4 per thread) ----
  {
    int s = tid >> 6;        // 64 float4 per sample row
    int c4 = tid & 63;
    float4 v = make_float4(0.f, 0.f, 0.f, 0.f);
    if (s0 + s < B)
      v = reinterpret_cast<const float4*>(x)[(size_t)(s0 + s) * 64 + c4];
    float* r = bufB + s * 1300 + c4 * 4;
    r[0] = v.x; r[1] = v.y; r[2] = v.z; r[3] = v.w;
  }
  __syncthreads();

  // ---- Layer 1: 8 blocks of (32 -> 325), o-tiles of 5 (325 % 5 == 0) ----
  {
    const float* W = ws + C0_OFF;
    for (int tile = tid; tile < 520; tile += NT) {
      int gb = tile * 5;
      int n = gb / 325;
      int oo = gb - n * 325;
      const float* w = W + (n * 32) * 325 + oo;
      const float* xin = bufB + n * 32;
      float acc[MT][5];
#pragma unroll
      for (int s = 0; s < MT; ++s)
#pragma unroll
        for (int j = 0; j < 5; ++j) acc[s][j] = 0.f;
      for (int m = 0; m < 32; ++m) {
        float wv[5];
#pragma unroll
        for (int j = 0; j < 5; ++j) wv[j] = w[m * 325 + j];
#pragma unroll
        for (int s = 0; s < MT; ++s) {
          float xv = xin[s * 1300 + m];
#pragma unroll
          for (int j = 0; j < 5; ++j) acc[s][j] += xv * wv[j];
        }
      }
#pragma unroll
      for (int s = 0; s < MT; ++s) {
        float* d = bufA + s * 2600 + gb;
#pragma unroll
        for (int j = 0; j < 5; ++j) d[j] = acc[s][j];
      }
    }
  }
  __syncthreads();

  // ---- Gate 1: bufA(2600) -> bufB(1300) ----
  {
    const float4* cf = reinterpret_cast<const float4*>(ws + CF_OFF);
    for (int g = tid; g < 1300; g += NT) {
      float4 c = cf[g];
#pragma unroll
      for (int s = 0; s < MT; ++s) {
        float2 ab = *reinterpret_cast<const float2*>(bufA + s * 2600 + 2 * g);
        bufB[s * 1300 + g] = c.x + c.y * ab.x + c.z * ab.y + c.w * (ab.x * ab.y);
      }
    }
  }
  __syncthreads();

  // ---- Layers 3 and 5 + gates: 50 blocks of (26 -> 52), o-tiles of 4 ----
#pragma unroll 1
  for (int L = 0; L < 2; ++L) {
    const float* W = ws + (L == 0 ? C1_OFF : C2_OFF);
    for (int tile = tid; tile < 650; tile += NT) {
      int gb = tile * 4;
      int n = gb / 52;
      int oo = gb - n * 52;
      const float* w = W + (n * 26) * 52 + oo;
      const float* xin = bufB + n * 26;
      float acc[MT][4];
#pragma unroll
      for (int s = 0; s < MT; ++s)
#pragma unroll
        for (int j = 0; j < 4; ++j) acc[s][j] = 0.f;
      for (int m = 0; m < 26; ++m) {
        float4 wv = *reinterpret_cast<const float4*>(w + m * 52);
#pragma unroll
        for (int s = 0; s < MT; ++s) {
          float xv = xin[s * 1300 + m];
          acc[s][0] += xv * wv.x;
          acc[s][1] += xv * wv.y;
          acc[s][2] += xv * wv.z;
          acc[s][3] += xv * wv.w;
        }
      }
#pragma unroll
      for (int s = 0; s < MT; ++s) {
        *reinterpret_cast<float4*>(bufA + s * 2600 + gb) =
            make_float4(acc[s][0], acc[s][1], acc[s][2], acc[s][3]);
      }
    }
    __syncthreads();
    const float4* cf =
        reinterpret_cast<const float4*>(ws + CF_OFF) + (L + 1) * 1300;
    for (int g = tid; g < 1300; g += NT) {
      float4 c = cf[g];
#pragma unroll
      for (int s = 0; s < MT; ++s) {
        float2 ab = *reinterpret_cast<const float2*>(bufA + s * 2600 + 2 * g);
        bufB[s * 1300 + g] = c.x + c.y * ab.x + c.z * ab.y + c.w * (ab.x * ab.y);
      }
    }
    __syncthreads();
  }

  // ---- logits: (1300) -> (10,130).sum ; then per-sample softmax ----
  if (tid < MT * 10) {
    int s = tid / 10, c = tid - s * 10;
    const float* src = bufB + s * 1300 + c * 130;
    float sum = 0.f;
    for (int j = 0; j < 130; ++j) sum += src[j];
    lg[s * 10 + c] = sum;
  }
  __syncthreads();
  if (tid < MT && s0 + tid < B) {
    int s = tid;
    float mx = lg[s * 10];
#pragma unroll
    for (int c = 1; c < 10; ++c) mx = fmaxf(mx, lg[s * 10 + c]);
    float e[10]; float ssum = 0.f;
#pragma unroll
    for (int c = 0; c < 10; ++c) { e[c] = __expf(lg[s * 10 + c] - mx); ssum += e[c]; }
    float inv = 1.f / ssum;
    float* o = out + (size_t)(s0 + s) * 10;
#pragma unroll
    for (int c = 0; c < 10; ++c) o[c] = e[c] * inv;
  }
}

extern "C" void kernel_launch(void* const* d_in, const int* in_sizes, int n_in,
                              void* d_out, int out_size, void* d_ws, size_t ws_size,
                              hipStream_t stream) {
  const float* x  = (const float*)d_in[0];
  const float* c0 = (const float*)d_in[1];
  const float* w0 = (const float*)d_in[2];
  const float* c1 = (const float*)d_in[3];
  const float* w1 = (const float*)d_in[4];
  const float* c2 = (const float*)d_in[5];
  const float* w2 = (const float*)d_in[6];
  float* out = (float*)d_out;
  float* ws  = (float*)d_ws;
  const int B = in_sizes[0] / 256;

  // 11,700 precompute work items
  precompute_kernel<<<46, 256, 0, stream>>>(c0, w0, c1, w1, c2, w2, ws);

  const size_t smem_bytes = (size_t)(MT * 2600 + MT * 1300 + MT * 10) * sizeof(float);
  hipFuncSetAttribute(reinterpret_cast<const void*>(fused_kernel),
                      hipFuncAttributeMaxDynamicSharedMemorySize, (int)smem_bytes);
  const int grid = (B + MT - 1) / MT;
  fused_kernel<<<grid, NT, smem_bytes, stream>>>(x, ws, out, B);
}